// Round 6
// baseline (42.955 us; speedup 1.0000x reference)
//
#include <hip/hip_runtime.h>
#include <hip/hip_bf16.h>
#include <math.h>

#define B_   2
#define N_   512
#define FN   128
#define FE   16
#define MID_ 128

typedef __attribute__((ext_vector_type(8)))  short short8_t;
typedef __attribute__((ext_vector_type(16))) float f32x16;

__device__ __forceinline__ short f2bf(float f) {
    __bf16 h = (__bf16)f;                    // fptrunc -> RNE bf16
    return __builtin_bit_cast(short, h);
}
// monotonic f32 -> u32 encode (order-preserving); max in u32 domain == fmax
__device__ __forceinline__ unsigned enc_f32(float f) {
    unsigned u = __float_as_uint(f);
    return u ^ (0x80000000u | (unsigned)((int)u >> 31));
}
__device__ __forceinline__ float dec_f32(unsigned u) {
    unsigned m = (u & 0x80000000u) ? 0x80000000u : 0xFFFFFFFFu;
    return __uint_as_float(u ^ m);
}
#define ENC_NEG_INF 0x007FFFFFu

// ---------------------------------------------------------------------------
// kA: msg1c = feat@W1+b1+(g@Wg+bg)+be ; msg2 = feat@W2+b2 ; h1 = feat@Wo1+bo1
// grid 512 = 2b x 256 tiles (2 rows); block 256: r=t>>7, m=t&127.
// (byte-identical to round 5 — presumed ~4 us; kept for attribution)
// ---------------------------------------------------------------------------
__global__ __launch_bounds__(256, 2) void kA(
    const float* __restrict__ feat, const float* __restrict__ gfeat,
    const float* __restrict__ W1, const float* __restrict__ b1,
    const float* __restrict__ W2, const float* __restrict__ b2,
    const float* __restrict__ be,
    const float* __restrict__ Wg, const float* __restrict__ bg,
    const float* __restrict__ Wo1, const float* __restrict__ bo1,
    float* __restrict__ msg1c, float* __restrict__ msg2, float* __restrict__ h1)
{
    __shared__ float fl[2 * FN];
    const int bid = blockIdx.x;          // 512 = 2b * 256 tiles
    const int b   = bid >> 8;
    const int n0  = (bid & 255) * 2;
    const int t   = threadIdx.x;
    const int r   = t >> 7, m = t & 127;

    if (t < 64)
        ((float4*)fl)[t] = ((const float4*)(feat + (size_t)(b * N_ + n0) * FN))[t];
    __syncthreads();

    const float* gb = gfeat + b * FN;
    float a1 = 0.f, a2 = 0.f, a3 = 0.f, mg = 0.f;
    for (int k0 = 0; k0 < FN; k0 += 8) {
        float w1v[8], w2v[8], w3v[8], wgv[8];
        #pragma unroll
        for (int u = 0; u < 8; ++u) {
            w1v[u] = W1 [(k0 + u) * MID_ + m];
            w2v[u] = W2 [(k0 + u) * MID_ + m];
            w3v[u] = Wo1[(k0 + u) * MID_ + m];
            wgv[u] = Wg [(k0 + u) * MID_ + m];
        }
        #pragma unroll
        for (int u = 0; u < 8; ++u) {
            const float f = fl[r * FN + k0 + u];
            a1 += f * w1v[u];
            a2 += f * w2v[u];
            a3 += f * w3v[u];
            mg += gb[k0 + u] * wgv[u];
        }
    }
    const size_t idx = (size_t)(b * N_ + n0 + r) * MID_ + m;
    msg1c[idx] = a1 + b1[m] + mg + bg[m] + be[m];
    msg2[idx]  = a2 + b2[m];
    h1[idx]    = a3 + bo1[m];
}

// ---------------------------------------------------------------------------
// kB round 6: wave = ALL 4 mt x 4 i (A-frag + sel masks amortize over 4 MFMAs);
// ef read direct global->reg (32 MB exact, no LDS round-trip); msg2 staged in
// LDS once; cross-wave merge via LDS ds_max enc-tile; epilogue folds
// c1 + 0-floor and stores f32 partials.
// grid 512 = 2b x 16jt x 16ic (32 i); block 512 = 8 waves.
// ---------------------------------------------------------------------------
__global__ __launch_bounds__(512, 4) void kB(
    const float* __restrict__ ef, const float* __restrict__ adj,
    const float* __restrict__ We,
    const float* __restrict__ msg1c, const float* __restrict__ msg2,
    float* __restrict__ part)
{
    __shared__ float    m2l[32 * MID_];    // 16 KB
    __shared__ unsigned tile[32 * MID_];   // 16 KB enc-u32 merge tile [jrow][m]
    __shared__ unsigned madj[32];
    __shared__ float    anyzf[32];

    const int bid = blockIdx.x;            // 512 = 2b * 16jt * 16ic
    const int b   = bid >> 8;
    const int jt  = (bid >> 4) & 15;
    const int ic  = bid & 15;
    const int j0  = jt * 32, i0 = ic * 32;
    const int t    = threadIdx.x;
    const int lane = t & 63, wid = t >> 6;
    const int g    = lane >> 5, lm = lane & 31;

    // stage msg2 chunk [32 i][128 m] (4096 floats, contiguous, coalesced)
    {
        const float4* src = (const float4*)(msg2 + (size_t)(b * N_ + i0) * MID_);
        ((float4*)m2l)[t]       = src[t];
        ((float4*)m2l)[t + 512] = src[t + 512];
    }
    // merge-tile init
    #pragma unroll
    for (int q = 0; q < 8; ++q) tile[t + 512 * q] = ENC_NEG_INF;
    // adj -> bitmasks via ballot (wave covers 4 i via 2 ballots)
    #pragma unroll
    for (int p = 0; p < 2; ++p) {
        const int i_l = wid * 4 + 2 * p + g;
        const float av = adj[(size_t)(b * N_ + i0 + i_l) * N_ + j0 + lm];
        const unsigned long long bal = __ballot(av != 0.0f);
        if (lane == 0)  madj[wid * 4 + 2 * p]     = (unsigned)bal;
        if (lane == 32) madj[wid * 4 + 2 * p + 1] = (unsigned)(bal >> 32);
    }
    // B fragments, all 4 mt: We[k=8g+jj, mt*32+lm]
    short8_t Bf[4];
    #pragma unroll
    for (int mt = 0; mt < 4; ++mt) {
        short8_t s;
        #pragma unroll
        for (int jj = 0; jj < 8; ++jj)
            s[jj] = f2bf(We[(8 * g + jj) * MID_ + mt * 32 + lm]);
        Bf[mt] = s;
    }

    f32x16 accm[4];
    #pragma unroll
    for (int mt = 0; mt < 4; ++mt)
        #pragma unroll
        for (int r = 0; r < 16; ++r) accm[mt][r] = -INFINITY;

    __syncthreads();

    if (t < 32) {   // all-ones-column -> -inf floor, else 0 (read after 2nd barrier)
        unsigned ao = 0xFFFFFFFFu;
        #pragma unroll
        for (int i2 = 0; i2 < 32; ++i2) ao &= madj[i2];
        anyzf[t] = ((ao >> t) & 1u) ? -INFINITY : 0.0f;
    }

    // prefetch + convert-early: A-fragments for this wave's 4 i
    const int ib = wid * 4;
    short8_t Afs[4];
    #pragma unroll
    for (int ii = 0; ii < 4; ++ii) {
        const float* efr = ef + ((size_t)(b * N_ + i0 + ib + ii) * N_ + j0 + lm) * FE + 8 * g;
        const float4 ea = *(const float4*)efr;
        const float4 eb = *(const float4*)(efr + 4);
        short8_t A;
        A[0] = f2bf(ea.x); A[1] = f2bf(ea.y); A[2] = f2bf(ea.z); A[3] = f2bf(ea.w);
        A[4] = f2bf(eb.x); A[5] = f2bf(eb.y); A[6] = f2bf(eb.z); A[7] = f2bf(eb.w);
        Afs[ii] = A;
    }

    #pragma unroll
    for (int ii = 0; ii < 4; ++ii) {
        const int i_l = ib + ii;
        const unsigned vm = madj[i_l] >> (4 * g);
        float m2v[4];
        #pragma unroll
        for (int mt = 0; mt < 4; ++mt) m2v[mt] = m2l[i_l * MID_ + mt * 32 + lm];
        #pragma unroll
        for (int mt = 0; mt < 4; ++mt) {
            f32x16 C;
            #pragma unroll
            for (int r = 0; r < 16; ++r) {
                const int cr = (r & 3) + 8 * (r >> 2);
                C[r] = (vm & (1u << cr)) ? m2v[mt] : -INFINITY;
            }
            const f32x16 S = __builtin_amdgcn_mfma_f32_32x32x16_bf16(Afs[ii], Bf[mt], C, 0, 0, 0);
            #pragma unroll
            for (int r = 0; r < 16; ++r) accm[mt][r] = fmaxf(accm[mt][r], S[r]);
        }
    }

    // cross-wave merge: LDS ds_max on enc values (order-independent)
    #pragma unroll
    for (int mt = 0; mt < 4; ++mt)
        #pragma unroll
        for (int r = 0; r < 16; ++r) {
            const int jrow = (r & 3) + 8 * (r >> 2) + 4 * g;
            atomicMax(&tile[jrow * MID_ + mt * 32 + lm], enc_f32(accm[mt][r]));
        }
    __syncthreads();

    // epilogue: dec + c1 + 0-floor, write f32 partial tile (coalesced)
    {
        const int jrow = t >> 4, m0 = (t & 15) * 8;
        const float az = anyzf[jrow];
        const float*  c1  = msg1c + (size_t)(b * N_ + j0 + jrow) * MID_ + m0;
        float*        dst = part  + ((size_t)(ic * 2 + b) * N_ + j0 + jrow) * MID_ + m0;
        const unsigned* tl = &tile[jrow * MID_ + m0];
        const float4 c1a = *(const float4*)c1;
        const float4 c1b = *(const float4*)(c1 + 4);
        float4 o0, o1;
        o0.x = fmaxf(dec_f32(tl[0]) + c1a.x, az);
        o0.y = fmaxf(dec_f32(tl[1]) + c1a.y, az);
        o0.z = fmaxf(dec_f32(tl[2]) + c1a.z, az);
        o0.w = fmaxf(dec_f32(tl[3]) + c1a.w, az);
        o1.x = fmaxf(dec_f32(tl[4]) + c1b.x, az);
        o1.y = fmaxf(dec_f32(tl[5]) + c1b.y, az);
        o1.z = fmaxf(dec_f32(tl[6]) + c1b.z, az);
        o1.w = fmaxf(dec_f32(tl[7]) + c1b.w, az);
        *(float4*)dst       = o0;
        *(float4*)(dst + 4) = o1;
    }
}

// ---------------------------------------------------------------------------
// kC: msgs = max over 16 f32 partials; out = h1 + msgs@Wo2 + bo2
// grid 512 = 2b x 256jt (2 rows); block 256: r=t>>7, o=t&127; 8-deep batches
// ---------------------------------------------------------------------------
__global__ __launch_bounds__(256, 2) void kC(
    const float* __restrict__ part, const float* __restrict__ h1,
    const float* __restrict__ Wo2, const float* __restrict__ bo2,
    float* __restrict__ out)
{
    __shared__ float ms[2 * MID_];
    const int bid = blockIdx.x;          // 512 = 2b * 256 tiles
    const int b   = bid >> 8;
    const int j0  = (bid & 255) * 2;
    const int t   = threadIdx.x;
    const int r   = t >> 7, m = t & 127;
    const size_t base = ((size_t)b * N_ + j0 + r) * MID_ + m;

    float u = -INFINITY;
    #pragma unroll
    for (int icc = 0; icc < 16; ++icc)
        u = fmaxf(u, part[(size_t)icc * 2 * N_ * MID_ + base]);
    ms[r * MID_ + m] = u;
    __syncthreads();

    float acc = h1[base] + bo2[m];
    for (int k0 = 0; k0 < MID_; k0 += 8) {
        float wv[8];
        #pragma unroll
        for (int uu = 0; uu < 8; ++uu) wv[uu] = Wo2[(k0 + uu) * MID_ + m];
        #pragma unroll
        for (int uu = 0; uu < 8; ++uu) acc += ms[r * MID_ + k0 + uu] * wv[uu];
    }
    out[base] = acc;
}

// ---------------------------------------------------------------------------
extern "C" void kernel_launch(void* const* d_in, const int* in_sizes, int n_in,
                              void* d_out, int out_size, void* d_ws, size_t ws_size,
                              hipStream_t stream)
{
    const float* feat = (const float*)d_in[0];
    const float* ef   = (const float*)d_in[1];
    const float* gf   = (const float*)d_in[2];
    const float* adj  = (const float*)d_in[3];
    const float* W1   = (const float*)d_in[4];
    const float* b1   = (const float*)d_in[5];
    const float* W2   = (const float*)d_in[6];
    const float* b2   = (const float*)d_in[7];
    const float* We   = (const float*)d_in[8];
    const float* be   = (const float*)d_in[9];
    const float* Wg   = (const float*)d_in[10];
    const float* bg   = (const float*)d_in[11];
    const float* Wo1  = (const float*)d_in[12];
    const float* bo1  = (const float*)d_in[13];
    const float* Wo2  = (const float*)d_in[14];
    const float* bo2  = (const float*)d_in[15];
    float* out = (float*)d_out;

    float* ws    = (float*)d_ws;
    float* msg1c = ws;                        // 131072 f32
    float* msg2  = ws + 131072;               // 131072 f32
    float* h1    = ws + 262144;               // 131072 f32
    float* part  = ws + 393216;               // 16ic*2b*512*128 f32 = 8 MB

    hipLaunchKernelGGL(kA, dim3(512), dim3(256), 0, stream,
        feat, gf, W1, b1, W2, b2, be, Wg, bg, Wo1, bo1, msg1c, msg2, h1);
    hipLaunchKernelGGL(kB, dim3(512), dim3(512), 0, stream,
        ef, adj, We, msg1c, msg2, part);
    hipLaunchKernelGGL(kC, dim3(512), dim3(256), 0, stream,
        part, h1, Wo2, bo2, out);
}

// Round 7
// 37.307 us; speedup vs baseline: 1.1514x; 1.1514x over previous
//
#include <hip/hip_runtime.h>
#include <hip/hip_bf16.h>
#include <math.h>

#define B_   2
#define N_   512
#define FN   128
#define FE   16
#define MID_ 128

typedef __attribute__((ext_vector_type(8)))  short short8_t;
typedef __attribute__((ext_vector_type(16))) float f32x16;

__device__ __forceinline__ short f2bf(float f) {
    __bf16 h = (__bf16)f;                    // fptrunc -> RNE bf16
    return __builtin_bit_cast(short, h);
}

// ---------------------------------------------------------------------------
// kA: msg1c = feat@W1+b1+(g@Wg+bg)+be ; msg2 = feat@W2+b2 ; h1 = feat@Wo1+bo1
// grid 512 = 2b x 256 tiles (2 rows); block 256 (byte-identical to round 6)
// ---------------------------------------------------------------------------
__global__ __launch_bounds__(256, 2) void kA(
    const float* __restrict__ feat, const float* __restrict__ gfeat,
    const float* __restrict__ W1, const float* __restrict__ b1,
    const float* __restrict__ W2, const float* __restrict__ b2,
    const float* __restrict__ be,
    const float* __restrict__ Wg, const float* __restrict__ bg,
    const float* __restrict__ Wo1, const float* __restrict__ bo1,
    float* __restrict__ msg1c, float* __restrict__ msg2, float* __restrict__ h1)
{
    __shared__ float fl[2 * FN];
    const int bid = blockIdx.x;          // 512 = 2b * 256 tiles
    const int b   = bid >> 8;
    const int n0  = (bid & 255) * 2;
    const int t   = threadIdx.x;
    const int r   = t >> 7, m = t & 127;

    if (t < 64)
        ((float4*)fl)[t] = ((const float4*)(feat + (size_t)(b * N_ + n0) * FN))[t];
    __syncthreads();

    const float* gb = gfeat + b * FN;
    float a1 = 0.f, a2 = 0.f, a3 = 0.f, mg = 0.f;
    for (int k0 = 0; k0 < FN; k0 += 8) {
        float w1v[8], w2v[8], w3v[8], wgv[8];
        #pragma unroll
        for (int u = 0; u < 8; ++u) {
            w1v[u] = W1 [(k0 + u) * MID_ + m];
            w2v[u] = W2 [(k0 + u) * MID_ + m];
            w3v[u] = Wo1[(k0 + u) * MID_ + m];
            wgv[u] = Wg [(k0 + u) * MID_ + m];
        }
        #pragma unroll
        for (int u = 0; u < 8; ++u) {
            const float f = fl[r * FN + k0 + u];
            a1 += f * w1v[u];
            a2 += f * w2v[u];
            a3 += f * w3v[u];
            mg += gb[k0 + u] * wgv[u];
        }
    }
    const size_t idx = (size_t)(b * N_ + n0 + r) * MID_ + m;
    msg1c[idx] = a1 + b1[m] + mg + bg[m] + be[m];
    msg2[idx]  = a2 + b2[m];
    h1[idx]    = a3 + bo1[m];
}

// ---------------------------------------------------------------------------
// kB round 7: spill-free. 8 waves = 4mt x 2ih; wave owns ONE mt, 16 i's.
// ef direct global->reg (mt-waves share rows via L2; HBM stays 32 MB exact).
// C-operand seeded m2v / -inf from ballot masks; pairwise LDS merge (no
// atomics, no enc); coalesced f32 epilogue (+c1, 0-floor) -> part.
// Peak VGPR ~75 (accm 16 + C 16 + A 8+8 + Bf 4 + misc) < 128 cap of (512,4).
// grid 512 = 2b x 16jt x 16ic.
// ---------------------------------------------------------------------------
__global__ __launch_bounds__(512, 4) void kB(
    const float* __restrict__ ef, const float* __restrict__ adj,
    const float* __restrict__ We,
    const float* __restrict__ msg1c, const float* __restrict__ msg2,
    float* __restrict__ part)
{
    __shared__ float    m2l[32 * MID_];    // 16 KB; reused as final tile after merge
    __shared__ float    mtile[4][32 * 32]; // 16 KB ih=1 partials
    __shared__ unsigned madj[32];
    __shared__ float    anyzf[32];

    const int bid = blockIdx.x;            // 512 = 2b * 16jt * 16ic
    const int b   = bid >> 8;
    const int jt  = (bid >> 4) & 15;
    const int ic  = bid & 15;
    const int j0  = jt * 32, i0 = ic * 32;
    const int t    = threadIdx.x;
    const int lane = t & 63, wid = t >> 6;
    const int mt   = wid & 3, ih = wid >> 2;
    const int g    = lane >> 5, lm = lane & 31;

    // stage msg2 chunk [32 i][128 m] (coalesced)
    {
        const float4* src = (const float4*)(msg2 + (size_t)(b * N_ + i0) * MID_);
        ((float4*)m2l)[t]       = src[t];
        ((float4*)m2l)[t + 512] = src[t + 512];
    }
    // adj -> bitmasks via ballot (wave covers 4 i via 2 ballots)
    #pragma unroll
    for (int p = 0; p < 2; ++p) {
        const int i_l = wid * 4 + 2 * p + g;
        const float av = adj[(size_t)(b * N_ + i0 + i_l) * N_ + j0 + lm];
        const unsigned long long bal = __ballot(av != 0.0f);
        if (lane == 0)  madj[wid * 4 + 2 * p]     = (unsigned)bal;
        if (lane == 32) madj[wid * 4 + 2 * p + 1] = (unsigned)(bal >> 32);
    }
    // B fragment for this wave's mt: We[k=8g+jj, mt*32+lm]
    short8_t Bf;
    #pragma unroll
    for (int jj = 0; jj < 8; ++jj)
        Bf[jj] = f2bf(We[(8 * g + jj) * MID_ + mt * 32 + lm]);

    f32x16 accm;
    #pragma unroll
    for (int r = 0; r < 16; ++r) accm[r] = -INFINITY;

    __syncthreads();

    if (t < 32) {   // all-ones column -> -inf floor, else 0 (read in epilogue)
        unsigned ao = 0xFFFFFFFFu;
        #pragma unroll
        for (int i2 = 0; i2 < 32; ++i2) ao &= madj[i2];
        anyzf[t] = ((ao >> t) & 1u) ? -INFINITY : 0.0f;
    }

    // main loop: this wave's 16 i's, one mt
    const float* efr = ef + (((size_t)(b * N_ + i0 + ih * 16)) * N_ + j0 + lm) * FE + 8 * g;
    #pragma unroll 2
    for (int ii = 0; ii < 16; ++ii) {
        const int i_l = ih * 16 + ii;
        const float4 ea = *(const float4*)efr;
        const float4 eb = *(const float4*)(efr + 4);
        efr += (size_t)N_ * FE;
        short8_t Af;
        Af[0] = f2bf(ea.x); Af[1] = f2bf(ea.y); Af[2] = f2bf(ea.z); Af[3] = f2bf(ea.w);
        Af[4] = f2bf(eb.x); Af[5] = f2bf(eb.y); Af[6] = f2bf(eb.z); Af[7] = f2bf(eb.w);

        const unsigned vmg = madj[i_l] >> (4 * g);
        const float m2v = m2l[i_l * MID_ + mt * 32 + lm];
        f32x16 C;
        #pragma unroll
        for (int r = 0; r < 16; ++r) {
            const int cr = (r & 3) + 8 * (r >> 2);
            C[r] = (vmg & (1u << cr)) ? m2v : -INFINITY;
        }
        const f32x16 S = __builtin_amdgcn_mfma_f32_32x32x16_bf16(Af, Bf, C, 0, 0, 0);
        #pragma unroll
        for (int r = 0; r < 16; ++r) accm[r] = fmaxf(accm[r], S[r]);
    }

    // pairwise cross-wave merge (no atomics)
    if (ih == 1) {
        #pragma unroll
        for (int r = 0; r < 16; ++r) {
            const int jrow = (r & 3) + 8 * (r >> 2) + 4 * g;
            mtile[mt][jrow * 32 + lm] = accm[r];
        }
    }
    __syncthreads();   // mtile ready; all m2l reads done -> safe to reuse as ftile
    float* ftile = m2l;
    if (ih == 0) {
        #pragma unroll
        for (int r = 0; r < 16; ++r) {
            const int jrow = (r & 3) + 8 * (r >> 2) + 4 * g;
            ftile[jrow * MID_ + mt * 32 + lm] = fmaxf(accm[r], mtile[mt][jrow * 32 + lm]);
        }
    }
    __syncthreads();

    // epilogue: +c1, 0-floor, coalesced f32 store
    {
        const int jrow = t >> 4, m0 = (t & 15) * 8;
        const float az = anyzf[jrow];
        const float*  c1  = msg1c + (size_t)(b * N_ + j0 + jrow) * MID_ + m0;
        float*        dst = part  + ((size_t)(ic * 2 + b) * N_ + j0 + jrow) * MID_ + m0;
        const float*  tl  = &ftile[jrow * MID_ + m0];
        const float4 c1a = *(const float4*)c1;
        const float4 c1b = *(const float4*)(c1 + 4);
        float4 o0, o1;
        o0.x = fmaxf(tl[0] + c1a.x, az);
        o0.y = fmaxf(tl[1] + c1a.y, az);
        o0.z = fmaxf(tl[2] + c1a.z, az);
        o0.w = fmaxf(tl[3] + c1a.w, az);
        o1.x = fmaxf(tl[4] + c1b.x, az);
        o1.y = fmaxf(tl[5] + c1b.y, az);
        o1.z = fmaxf(tl[6] + c1b.z, az);
        o1.w = fmaxf(tl[7] + c1b.w, az);
        *(float4*)dst       = o0;
        *(float4*)(dst + 4) = o1;
    }
}

// ---------------------------------------------------------------------------
// kC: msgs = max over 16 f32 partials; out = h1 + msgs@Wo2 + bo2
// grid 512 = 2b x 256jt (2 rows); block 256 (byte-identical to round 6)
// ---------------------------------------------------------------------------
__global__ __launch_bounds__(256, 2) void kC(
    const float* __restrict__ part, const float* __restrict__ h1,
    const float* __restrict__ Wo2, const float* __restrict__ bo2,
    float* __restrict__ out)
{
    __shared__ float ms[2 * MID_];
    const int bid = blockIdx.x;          // 512 = 2b * 256 tiles
    const int b   = bid >> 8;
    const int j0  = (bid & 255) * 2;
    const int t   = threadIdx.x;
    const int r   = t >> 7, m = t & 127;
    const size_t base = ((size_t)b * N_ + j0 + r) * MID_ + m;

    float u = -INFINITY;
    #pragma unroll
    for (int icc = 0; icc < 16; ++icc)
        u = fmaxf(u, part[(size_t)icc * 2 * N_ * MID_ + base]);
    ms[r * MID_ + m] = u;
    __syncthreads();

    float acc = h1[base] + bo2[m];
    for (int k0 = 0; k0 < MID_; k0 += 8) {
        float wv[8];
        #pragma unroll
        for (int uu = 0; uu < 8; ++uu) wv[uu] = Wo2[(k0 + uu) * MID_ + m];
        #pragma unroll
        for (int uu = 0; uu < 8; ++uu) acc += ms[r * MID_ + k0 + uu] * wv[uu];
    }
    out[base] = acc;
}

// ---------------------------------------------------------------------------
extern "C" void kernel_launch(void* const* d_in, const int* in_sizes, int n_in,
                              void* d_out, int out_size, void* d_ws, size_t ws_size,
                              hipStream_t stream)
{
    const float* feat = (const float*)d_in[0];
    const float* ef   = (const float*)d_in[1];
    const float* gf   = (const float*)d_in[2];
    const float* adj  = (const float*)d_in[3];
    const float* W1   = (const float*)d_in[4];
    const float* b1   = (const float*)d_in[5];
    const float* W2   = (const float*)d_in[6];
    const float* b2   = (const float*)d_in[7];
    const float* We   = (const float*)d_in[8];
    const float* be   = (const float*)d_in[9];
    const float* Wg   = (const float*)d_in[10];
    const float* bg   = (const float*)d_in[11];
    const float* Wo1  = (const float*)d_in[12];
    const float* bo1  = (const float*)d_in[13];
    const float* Wo2  = (const float*)d_in[14];
    const float* bo2  = (const float*)d_in[15];
    float* out = (float*)d_out;

    float* ws    = (float*)d_ws;
    float* msg1c = ws;                        // 131072 f32
    float* msg2  = ws + 131072;               // 131072 f32
    float* h1    = ws + 262144;               // 131072 f32
    float* part  = ws + 393216;               // 16ic*2b*512*128 f32 = 8 MB

    hipLaunchKernelGGL(kA, dim3(512), dim3(256), 0, stream,
        feat, gf, W1, b1, W2, b2, be, Wg, bg, Wo1, bo1, msg1c, msg2, h1);
    hipLaunchKernelGGL(kB, dim3(512), dim3(512), 0, stream,
        ef, adj, We, msg1c, msg2, part);
    hipLaunchKernelGGL(kC, dim3(512), dim3(256), 0, stream,
        part, h1, Wo2, bo2, out);
}